// Round 3
// baseline (210.932 us; speedup 1.0000x reference)
//
#include <hip/hip_runtime.h>
#include <hip/hip_cooperative_groups.h>
#include <math.h>

namespace cg = cooperative_groups;

// Problem shape (fixed by setup_inputs): x [B,T,D] fp32, w [D,1], b [1]
#define B  16
#define T  2048
#define D  512
#define NS 64            // segments along T
#define L  (T / NS)      // 32 rows per segment
#define D4 (D / 4)       // 128 float4 per row

__device__ __forceinline__ void fma4(float4& a, float s, const float4& v) {
    a.x = fmaf(s, v.x, a.x); a.y = fmaf(s, v.y, a.y);
    a.z = fmaf(s, v.z, a.z); a.w = fmaf(s, v.w, a.w);
}

// ---------------------------------------------------------------------------
// Fused cooperative kernel. 1024 blocks = (b, k-segment), 256 thr = 4 waves.
// Phase 1: block holds its 32x512 x-tile in VGPRs; computes s_j, segment max
//          m_k, e_j = exp(s_j - m_k), q_k = sum e_j, V_k = sum e_j x_j.
//          Writes m, q, V to workspace.   (x read from HBM exactly once)
// grid.sync()
// Phase 2: block re-derives batch max M_b, scales sc_k' = exp(m_k'-M_b),
//          scalar prefix Q_excl, vector seed P_k = sum_{k'<k} sc·V_k' (L2).
// Phase 3: seeded running scan over the register-resident x-tile; writes out.
// ---------------------------------------------------------------------------
__global__ __launch_bounds__(256, 4) void fused_kernel(
        const float* __restrict__ x, const float* __restrict__ w,
        const float* __restrict__ bias,
        float* __restrict__ m_g, float* __restrict__ q_g,
        float* __restrict__ V, float* __restrict__ out) {
    const int blk = blockIdx.x;
    const int b = blk >> 6, k = blk & (NS - 1);
    const int t0 = k * L;
    const int tid = threadIdx.x, lane = tid & 63, wv = tid >> 6;

    const float4* x4 = (const float4*)x + ((size_t)b * T + t0) * D4;
    const float4* w4 = (const float4*)w;
    const float4 w0 = w4[lane], w1 = w4[lane + 64];

    float4 xr0[8], xr1[8];
    float dots[8];
#pragma unroll
    for (int r = 0; r < 8; ++r) {
        const int j = wv * 8 + r;
        xr0[r] = x4[(size_t)j * D4 + lane];
        xr1[r] = x4[(size_t)j * D4 + lane + 64];
        dots[r] = xr0[r].x * w0.x + xr0[r].y * w0.y + xr0[r].z * w0.z + xr0[r].w * w0.w +
                  xr1[r].x * w1.x + xr1[r].y * w1.y + xr1[r].z * w1.z + xr1[r].w * w1.w;
    }

    __shared__ float s_sh[L], e_sh[L];
    __shared__ float accbuf[4][D];
    __shared__ float sc_sh[NS];
    __shared__ float wl[L], il[L];

#pragma unroll
    for (int r = 0; r < 8; ++r) {
        float d = dots[r];
#pragma unroll
        for (int off = 32; off > 0; off >>= 1) d += __shfl_xor(d, off);
        if (lane == 0) s_sh[wv * 8 + r] = d + bias[0];
    }
    __syncthreads();

    float mk = -1e30f;
#pragma unroll
    for (int j = 0; j < L; ++j) mk = fmaxf(mk, s_sh[j]);

    float4 a0 = {0.f, 0.f, 0.f, 0.f}, a1 = {0.f, 0.f, 0.f, 0.f};
#pragma unroll
    for (int r = 0; r < 8; ++r) {
        const float e = __expf(s_sh[wv * 8 + r] - mk);
        if (lane == 0) e_sh[wv * 8 + r] = e;
        fma4(a0, e, xr0[r]); fma4(a1, e, xr1[r]);
    }
    ((float4*)accbuf[wv])[lane]      = a0;
    ((float4*)accbuf[wv])[lane + 64] = a1;
    __syncthreads();

    if (tid < 128) {
        const float4 r0 = ((float4*)accbuf[0])[tid];
        const float4 r1 = ((float4*)accbuf[1])[tid];
        const float4 r2 = ((float4*)accbuf[2])[tid];
        const float4 r3 = ((float4*)accbuf[3])[tid];
        float4 rr;
        rr.x = (r0.x + r1.x) + (r2.x + r3.x);
        rr.y = (r0.y + r1.y) + (r2.y + r3.y);
        rr.z = (r0.z + r1.z) + (r2.z + r3.z);
        rr.w = (r0.w + r1.w) + (r2.w + r3.w);
        ((float4*)V)[((size_t)b * NS + k) * D4 + tid] = rr;
    } else if (tid == 128) {
        m_g[b * NS + k] = mk;
        float q = 0.f;
#pragma unroll
        for (int j = 0; j < L; ++j) q += e_sh[j];
        q_g[b * NS + k] = q;
    }

    __threadfence();
    cg::this_grid().sync();

    // -------- Phase 2: per-wave redundant scalar combine --------
    const float m_i = m_g[b * NS + lane];
    const float q_i = q_g[b * NS + lane];
    float M = m_i;
#pragma unroll
    for (int off = 32; off > 0; off >>= 1) M = fmaxf(M, __shfl_xor(M, off));
    const float sc_i = __expf(m_i - M);
    const float qp = sc_i * q_i;
    float incl = qp;
#pragma unroll
    for (int off = 1; off < 64; off <<= 1) {
        const float t = __shfl_up(incl, off);
        if (lane >= off) incl += t;
    }
    const float Qexcl = __shfl(incl - qp, k);   // sum_{k'<k} sc q
    const float sck   = __shfl(sc_i, k);
    if (wv == 0) sc_sh[lane] = sc_i;
    __syncthreads();

    // vector seed: waves split the k' range, LDS-reduce
    float4 s0 = {0.f, 0.f, 0.f, 0.f}, s1 = {0.f, 0.f, 0.f, 0.f};
    for (int kp = wv; kp < k; kp += 4) {
        const float sc = sc_sh[kp];
        const float4* Vp = (const float4*)V + ((size_t)b * NS + kp) * D4;
        fma4(s0, sc, Vp[lane]);
        fma4(s1, sc, Vp[lane + 64]);
    }
    ((float4*)accbuf[wv])[lane]      = s0;
    ((float4*)accbuf[wv])[lane + 64] = s1;

    if (wv == 0) {   // per-row weights and inverse denominators
        const float e_j = (lane < L) ? e_sh[lane] : 0.f;
        float ce = e_j;
#pragma unroll
        for (int off = 1; off < 32; off <<= 1) {
            const float t = __shfl_up(ce, off);
            if (lane >= off) ce += t;
        }
        if (lane < L) {
            wl[lane] = sck * e_j;
            il[lane] = 1.0f / fmaf(sck, ce, Qexcl);
        }
    }
    __syncthreads();

    float4 seed0, seed1;
    {
        const float4 c0 = ((float4*)accbuf[0])[lane];
        const float4 c1 = ((float4*)accbuf[1])[lane];
        const float4 c2 = ((float4*)accbuf[2])[lane];
        const float4 c3 = ((float4*)accbuf[3])[lane];
        seed0.x = (c0.x + c1.x) + (c2.x + c3.x);
        seed0.y = (c0.y + c1.y) + (c2.y + c3.y);
        seed0.z = (c0.z + c1.z) + (c2.z + c3.z);
        seed0.w = (c0.w + c1.w) + (c2.w + c3.w);
        const float4 d0 = ((float4*)accbuf[0])[lane + 64];
        const float4 d1 = ((float4*)accbuf[1])[lane + 64];
        const float4 d2 = ((float4*)accbuf[2])[lane + 64];
        const float4 d3 = ((float4*)accbuf[3])[lane + 64];
        seed1.x = (d0.x + d1.x) + (d2.x + d3.x);
        seed1.y = (d0.y + d1.y) + (d2.y + d3.y);
        seed1.z = (d0.z + d1.z) + (d2.z + d3.z);
        seed1.w = (d0.w + d1.w) + (d2.w + d3.w);
    }

    // -------- Phase 3: seeded scan over register-resident tile --------
    float wcr[8];
    float4 t0v = {0.f, 0.f, 0.f, 0.f}, t1v = {0.f, 0.f, 0.f, 0.f};
#pragma unroll
    for (int r = 0; r < 8; ++r) {
        wcr[r] = wl[wv * 8 + r];
        fma4(t0v, wcr[r], xr0[r]); fma4(t1v, wcr[r], xr1[r]);
    }
    __syncthreads();                       // seeds fully read
    ((float4*)accbuf[wv])[lane]      = t0v;
    ((float4*)accbuf[wv])[lane + 64] = t1v;
    __syncthreads();

    float4 p0 = seed0, p1 = seed1;
    for (int w2 = 0; w2 < wv; ++w2) {      // wave-uniform loop
        const float4 c0 = ((float4*)accbuf[w2])[lane];
        const float4 c1 = ((float4*)accbuf[w2])[lane + 64];
        p0.x += c0.x; p0.y += c0.y; p0.z += c0.z; p0.w += c0.w;
        p1.x += c1.x; p1.y += c1.y; p1.z += c1.z; p1.w += c1.w;
    }

    float4* outb = (float4*)out + (size_t)b * T * D4;
    if (k == 0 && wv == 0) {               // out[b,0,:] = x[b,0,:]
        outb[lane]      = xr0[0];
        outb[lane + 64] = xr1[0];
    }
#pragma unroll
    for (int r = 0; r < 8; ++r) {
        fma4(p0, wcr[r], xr0[r]); fma4(p1, wcr[r], xr1[r]);
        const int t = t0 + wv * 8 + r;
        if (t < T - 1) {
            const float idn = il[wv * 8 + r];
            float4 o0, o1;
            o0.x = p0.x * idn; o0.y = p0.y * idn; o0.z = p0.z * idn; o0.w = p0.w * idn;
            o1.x = p1.x * idn; o1.y = p1.y * idn; o1.z = p1.z * idn; o1.w = p1.w * idn;
            outb[(size_t)(t + 1) * D4 + lane]      = o0;
            outb[(size_t)(t + 1) * D4 + lane + 64] = o1;
        }
    }
}

// ===========================================================================
// Fallback path (proven R2 3-kernel pipeline) in case cooperative launch is
// rejected (occupancy validation). Identical math.
// ===========================================================================
__global__ __launch_bounds__(256) void seg_kernel(const float* __restrict__ x,
                                                  const float* __restrict__ w,
                                                  const float* __restrict__ bias,
                                                  float* __restrict__ p_loc,
                                                  float* __restrict__ m_out,
                                                  float* __restrict__ q_out,
                                                  float* __restrict__ V) {
    int b = blockIdx.x / NS, k = blockIdx.x % NS;
    int t0 = k * L;
    int tid = threadIdx.x, lane = tid & 63, wv = tid >> 6;
    const float4* x4 = (const float4*)x + ((size_t)b * T + t0) * D4;
    const float4* w4 = (const float4*)w;
    float4 w0 = w4[lane], w1 = w4[lane + 64];

    float4 xr0[8], xr1[8];
    float dots[8];
#pragma unroll
    for (int r = 0; r < 8; ++r) {
        int j = wv * 8 + r;
        xr0[r] = x4[(size_t)j * D4 + lane];
        xr1[r] = x4[(size_t)j * D4 + lane + 64];
        dots[r] = xr0[r].x * w0.x + xr0[r].y * w0.y + xr0[r].z * w0.z + xr0[r].w * w0.w +
                  xr1[r].x * w1.x + xr1[r].y * w1.y + xr1[r].z * w1.z + xr1[r].w * w1.w;
    }

    __shared__ float s_sh[L], e_sh[L];
    __shared__ float accbuf[4][D];

#pragma unroll
    for (int r = 0; r < 8; ++r) {
        float d = dots[r];
#pragma unroll
        for (int off = 32; off > 0; off >>= 1) d += __shfl_xor(d, off);
        if (lane == 0) s_sh[wv * 8 + r] = d + bias[0];
    }
    __syncthreads();

    float mk = -1e30f;
#pragma unroll
    for (int j = 0; j < L; ++j) mk = fmaxf(mk, s_sh[j]);

    float4 a0 = {0.f, 0.f, 0.f, 0.f}, a1 = {0.f, 0.f, 0.f, 0.f};
#pragma unroll
    for (int r = 0; r < 8; ++r) {
        float e = __expf(s_sh[wv * 8 + r] - mk);
        if (lane == 0) e_sh[wv * 8 + r] = e;
        fma4(a0, e, xr0[r]); fma4(a1, e, xr1[r]);
    }
    ((float4*)accbuf[wv])[lane]      = a0;
    ((float4*)accbuf[wv])[lane + 64] = a1;
    __syncthreads();

    if (tid < 128) {
        float4 s0 = ((float4*)accbuf[0])[tid];
        float4 s1 = ((float4*)accbuf[1])[tid];
        float4 s2 = ((float4*)accbuf[2])[tid];
        float4 s3 = ((float4*)accbuf[3])[tid];
        float4 r;
        r.x = (s0.x + s1.x) + (s2.x + s3.x);
        r.y = (s0.y + s1.y) + (s2.y + s3.y);
        r.z = (s0.z + s1.z) + (s2.z + s3.z);
        r.w = (s0.w + s1.w) + (s2.w + s3.w);
        ((float4*)V)[((size_t)b * NS + k) * D4 + tid] = r;
    }
    if (tid < L) p_loc[(size_t)b * T + t0 + tid] = e_sh[tid];
    if (tid == 0) {
        m_out[b * NS + k] = mk;
        float q = 0.f;
#pragma unroll
        for (int j = 0; j < L; ++j) q += e_sh[j];
        q_out[b * NS + k] = q;
    }
}

__global__ __launch_bounds__(256) void mid_kernel(const float* __restrict__ p_loc,
                                                  const float* __restrict__ m_in,
                                                  const float* __restrict__ q_in,
                                                  const float* __restrict__ V,
                                                  float* __restrict__ P,
                                                  float* __restrict__ wcoef,
                                                  float* __restrict__ invden) {
    __shared__ float4 buf4[256];
    __shared__ float sm[NS];
    __shared__ float Qsh[NS];
    __shared__ float tsum[256];
    int tid = threadIdx.x;

    if (blockIdx.x < B) {
        int b = blockIdx.x;
        if (tid < 64) {
            float mk = m_in[b * NS + tid];
            float M = mk;
#pragma unroll
            for (int off = 32; off > 0; off >>= 1) M = fmaxf(M, __shfl_xor(M, off));
            float sc = __expf(mk - M);
            float qp = sc * q_in[b * NS + tid];
            float incl = qp;
#pragma unroll
            for (int off = 1; off < 64; off <<= 1) {
                float t = __shfl_up(incl, off);
                if (tid >= off) incl += t;
            }
            sm[tid]  = sc;
            Qsh[tid] = incl - qp;
        }
        const float4* pp = (const float4*)(p_loc + (size_t)b * T);
        float4 pv0 = pp[tid * 2], pv1 = pp[tid * 2 + 1];
        float p[8] = {pv0.x, pv0.y, pv0.z, pv0.w, pv1.x, pv1.y, pv1.z, pv1.w};
        float pf[8];
        float run = 0.f;
#pragma unroll
        for (int i = 0; i < 8; ++i) { run += p[i]; pf[i] = run; }
        tsum[tid] = run;
        __syncthreads();
        int g = tid & 3, base = tid & ~3;
        float excl = 0.f;
        if (g > 0) excl += tsum[base + 0];
        if (g > 1) excl += tsum[base + 1];
        if (g > 2) excl += tsum[base + 2];
        int kk = tid >> 2;
        float sc = sm[kk], Q = Qsh[kk];
        float od[8], wc[8];
#pragma unroll
        for (int i = 0; i < 8; ++i) {
            od[i] = 1.0f / (Q + sc * (excl + pf[i]));
            wc[i] = sc * p[i];
        }
        float4* wcp = (float4*)(wcoef + (size_t)b * T) + tid * 2;
        float4* idp = (float4*)(invden + (size_t)b * T) + tid * 2;
        float4 t0v; t0v.x = wc[0]; t0v.y = wc[1]; t0v.z = wc[2]; t0v.w = wc[3];
        float4 t1v; t1v.x = wc[4]; t1v.y = wc[5]; t1v.z = wc[6]; t1v.w = wc[7];
        wcp[0] = t0v; wcp[1] = t1v;
        float4 u0; u0.x = od[0]; u0.y = od[1]; u0.z = od[2]; u0.w = od[3];
        float4 u1; u1.x = od[4]; u1.y = od[5]; u1.z = od[6]; u1.w = od[7];
        idp[0] = u0; idp[1] = u1;
    } else {
        int idx = blockIdx.x - B;
        int b = idx >> 5, c = idx & 31;
        int k = tid >> 2, cc = tid & 3, d4 = c * 4 + cc;
        if (tid < NS) sm[tid] = m_in[b * NS + tid];
        __syncthreads();
        float M = -1e30f;
#pragma unroll
        for (int i = 0; i < NS; ++i) M = fmaxf(M, sm[i]);
        float sc = __expf(sm[k] - M);
        float4 v = ((const float4*)V)[((size_t)b * NS + k) * D4 + d4];
        v.x *= sc; v.y *= sc; v.z *= sc; v.w *= sc;
        buf4[tid] = v;
        __syncthreads();
        float4 run = v;
        for (int off = 1; off < NS; off <<= 1) {
            float4 t = {0.f, 0.f, 0.f, 0.f};
            if (k >= off) t = buf4[tid - 4 * off];
            __syncthreads();
            run.x += t.x; run.y += t.y; run.z += t.z; run.w += t.w;
            buf4[tid] = run;
            __syncthreads();
        }
        float4 ex; ex.x = run.x - v.x; ex.y = run.y - v.y; ex.z = run.z - v.z; ex.w = run.w - v.w;
        ((float4*)P)[((size_t)b * NS + k) * D4 + d4] = ex;
    }
}

__global__ __launch_bounds__(128) void output_kernel(const float* __restrict__ x,
                                                     const float* __restrict__ wcoef,
                                                     const float* __restrict__ invden,
                                                     const float* __restrict__ P,
                                                     float* __restrict__ out) {
    int b = blockIdx.x / NS, k = blockIdx.x % NS;
    int t0 = k * L;
    int d4 = threadIdx.x;
    const float4* x4 = (const float4*)x + ((size_t)b * T + t0) * D4;
    float4* out4 = (float4*)out + (size_t)b * T * D4;

    __shared__ float wl[L], il[L];
    if (threadIdx.x < L) {
        wl[threadIdx.x] = wcoef[(size_t)b * T + t0 + threadIdx.x];
        il[threadIdx.x] = invden[(size_t)b * T + t0 + threadIdx.x];
    }
    __syncthreads();

    float4 a = ((const float4*)P)[((size_t)b * NS + k) * D4 + d4];

    if (k == 0) {
        out4[d4] = ((const float4*)x)[(size_t)b * T * D4 + d4];
    }

#pragma unroll 4
    for (int j = 0; j < L; ++j) {
        float4 xv = x4[(size_t)j * D4 + d4];
        float pj = wl[j];
        a.x += pj * xv.x; a.y += pj * xv.y; a.z += pj * xv.z; a.w += pj * xv.w;
        int t = t0 + j;
        if (t < T - 1) {
            float idn = il[j];
            float4 r; r.x = a.x * idn; r.y = a.y * idn; r.z = a.z * idn; r.w = a.w * idn;
            out4[(size_t)(t + 1) * D4 + d4] = r;
        }
    }
}

// ---------------------------------------------------------------------------
extern "C" void kernel_launch(void* const* d_in, const int* in_sizes, int n_in,
                              void* d_out, int out_size, void* d_ws, size_t ws_size,
                              hipStream_t stream) {
    const float* x    = (const float*)d_in[0];
    const float* w    = (const float*)d_in[1];
    const float* bias = (const float*)d_in[2];
    float* out = (float*)d_out;

    // workspace layout (fp32):
    // p_loc[B*T] | wcoef[B*T] | invden[B*T] | m[B*NS] | q[B*NS] | V[B*NS*D] | P[B*NS*D]
    float* p_loc  = (float*)d_ws;
    float* wcoef  = p_loc  + (size_t)B * T;
    float* invden = wcoef  + (size_t)B * T;
    float* m      = invden + (size_t)B * T;
    float* q      = m      + (size_t)B * NS;
    float* V      = q      + (size_t)B * NS;
    float* P      = V      + (size_t)B * NS * D;

    void* args[] = {(void*)&x, (void*)&w, (void*)&bias,
                    (void*)&m, (void*)&q, (void*)&V, (void*)&out};
    hipError_t err = hipLaunchCooperativeKernel((const void*)fused_kernel,
                                                dim3(B * NS), dim3(256),
                                                args, 0, stream);
    if (err != hipSuccess) {
        // deterministic fallback: proven 3-kernel pipeline
        seg_kernel   <<<B * NS,           256, 0, stream>>>(x, w, bias, p_loc, m, q, V);
        mid_kernel   <<<B + B * (D4 / 4), 256, 0, stream>>>(p_loc, m, q, V, P, wcoef, invden);
        output_kernel<<<B * NS,           128, 0, stream>>>(x, wcoef, invden, P, out);
    }
}

// Round 4
// 41.055 us; speedup vs baseline: 5.1378x; 5.1378x over previous
//
#include <hip/hip_runtime.h>
#include <math.h>

// Problem shape (fixed by setup_inputs): x [B,T,D] fp32, w [D,1], b [1]
#define B  16
#define T  2048
#define D  512
#define NS 64            // segments along T
#define L  (T / NS)      // 32 rows per segment
#define D4 (D / 4)       // 128 float4 per row

__device__ __forceinline__ void fma4(float4& a, float s, const float4& v) {
    a.x = fmaf(s, v.x, a.x); a.y = fmaf(s, v.y, a.y);
    a.z = fmaf(s, v.z, a.z); a.w = fmaf(s, v.w, a.w);
}

// ---------------------------------------------------------------------------
// K1: per (batch, segment) block (256 thr = 4 waves, 8 rows/wave):
//   s_j = dot(x_j, w) + bias ; m_k = max s ; e_j = exp(s_j - m_k)
//   q_k = sum e_j ; V_k = sum e_j x_j      (x read from HBM exactly once)
// ---------------------------------------------------------------------------
__global__ __launch_bounds__(256) void seg_kernel(const float* __restrict__ x,
                                                  const float* __restrict__ w,
                                                  const float* __restrict__ bias,
                                                  float* __restrict__ p_loc,
                                                  float* __restrict__ m_out,
                                                  float* __restrict__ q_out,
                                                  float* __restrict__ V) {
    int b = blockIdx.x / NS, k = blockIdx.x % NS;
    int t0 = k * L;
    int tid = threadIdx.x, lane = tid & 63, wv = tid >> 6;
    const float4* x4 = (const float4*)x + ((size_t)b * T + t0) * D4;
    const float4* w4 = (const float4*)w;
    float4 w0 = w4[lane], w1 = w4[lane + 64];

    float4 xr0[8], xr1[8];
    float dots[8];
#pragma unroll
    for (int r = 0; r < 8; ++r) {
        int j = wv * 8 + r;
        xr0[r] = x4[(size_t)j * D4 + lane];
        xr1[r] = x4[(size_t)j * D4 + lane + 64];
        dots[r] = xr0[r].x * w0.x + xr0[r].y * w0.y + xr0[r].z * w0.z + xr0[r].w * w0.w +
                  xr1[r].x * w1.x + xr1[r].y * w1.y + xr1[r].z * w1.z + xr1[r].w * w1.w;
    }

    __shared__ float s_sh[L], e_sh[L];
    __shared__ float accbuf[4][D];

#pragma unroll
    for (int r = 0; r < 8; ++r) {
        float d = dots[r];
#pragma unroll
        for (int off = 32; off > 0; off >>= 1) d += __shfl_xor(d, off);
        if (lane == 0) s_sh[wv * 8 + r] = d + bias[0];
    }
    __syncthreads();

    float mk = -1e30f;
#pragma unroll
    for (int j = 0; j < L; ++j) mk = fmaxf(mk, s_sh[j]);

    float4 a0 = {0.f, 0.f, 0.f, 0.f}, a1 = {0.f, 0.f, 0.f, 0.f};
#pragma unroll
    for (int r = 0; r < 8; ++r) {
        float e = __expf(s_sh[wv * 8 + r] - mk);
        if (lane == 0) e_sh[wv * 8 + r] = e;
        fma4(a0, e, xr0[r]); fma4(a1, e, xr1[r]);
    }
    ((float4*)accbuf[wv])[lane]      = a0;
    ((float4*)accbuf[wv])[lane + 64] = a1;
    __syncthreads();

    if (tid < 128) {
        float4 s0 = ((float4*)accbuf[0])[tid];
        float4 s1 = ((float4*)accbuf[1])[tid];
        float4 s2 = ((float4*)accbuf[2])[tid];
        float4 s3 = ((float4*)accbuf[3])[tid];
        float4 r;
        r.x = (s0.x + s1.x) + (s2.x + s3.x);
        r.y = (s0.y + s1.y) + (s2.y + s3.y);
        r.z = (s0.z + s1.z) + (s2.z + s3.z);
        r.w = (s0.w + s1.w) + (s2.w + s3.w);
        ((float4*)V)[((size_t)b * NS + k) * D4 + tid] = r;
    }
    if (tid < L) p_loc[(size_t)b * T + t0 + tid] = e_sh[tid];
    if (tid == 0) {
        m_out[b * NS + k] = mk;
        float q = 0.f;
#pragma unroll
        for (int j = 0; j < L; ++j) q += e_sh[j];
        q_out[b * NS + k] = q;
    }
}

// ---------------------------------------------------------------------------
// K2: fused combine + output. Per (batch, segment) block, 256 thr = 4 waves,
// 8 rows/wave held in registers (single kernel, no sync boundary -> no spill).
//  1. per-wave redundant scalar combine: M_b, sc_k', Qexcl_k, sck (shuffles)
//  2. vector seed P_k = sum_{k'<k} sc_k' V[b,k',:]  (V is L2-resident, 2 MB)
//  3. per-row weights wl_j = sck*e_j, invden il_j = 1/(Qexcl + sck*prefix(e))
//  4. per-wave partial of its 8 rows, LDS exchange, seeded scan, write out.
// ---------------------------------------------------------------------------
__global__ __launch_bounds__(256) void out_kernel(const float* __restrict__ x,
                                                  const float* __restrict__ p_loc,
                                                  const float* __restrict__ m_g,
                                                  const float* __restrict__ q_g,
                                                  const float* __restrict__ V,
                                                  float* __restrict__ out) {
    const int blk = blockIdx.x;
    const int b = blk >> 6, k = blk & (NS - 1);
    const int t0 = k * L;
    const int tid = threadIdx.x, lane = tid & 63, wv = tid >> 6;

    // issue x-tile loads early; held in VGPRs for the whole kernel
    const float4* x4 = (const float4*)x + ((size_t)b * T + t0) * D4;
    float4 xr0[8], xr1[8];
#pragma unroll
    for (int r = 0; r < 8; ++r) {
        const int j = wv * 8 + r;
        xr0[r] = x4[(size_t)j * D4 + lane];
        xr1[r] = x4[(size_t)j * D4 + lane + 64];
    }

    __shared__ float accbuf[4][D];
    __shared__ float sc_sh[NS];
    __shared__ float wl[L], il[L];

    // ---- 1. scalar combine (per-wave redundant) ----
    const float m_i = m_g[b * NS + lane];
    const float q_i = q_g[b * NS + lane];
    float M = m_i;
#pragma unroll
    for (int off = 32; off > 0; off >>= 1) M = fmaxf(M, __shfl_xor(M, off));
    const float sc_i = __expf(m_i - M);
    const float qp = sc_i * q_i;
    float incl = qp;
#pragma unroll
    for (int off = 1; off < 64; off <<= 1) {
        const float t = __shfl_up(incl, off);
        if (lane >= off) incl += t;
    }
    const float Qexcl = __shfl(incl - qp, k);   // sum_{k'<k} sc*q
    const float sck   = __shfl(sc_i, k);
    if (wv == 0) sc_sh[lane] = sc_i;
    __syncthreads();

    // ---- 2. vector seed: waves split k' range ----
    float4 s0 = {0.f, 0.f, 0.f, 0.f}, s1 = {0.f, 0.f, 0.f, 0.f};
    for (int kp = wv; kp < k; kp += 4) {
        const float sc = sc_sh[kp];
        const float4* Vp = (const float4*)V + ((size_t)b * NS + kp) * D4;
        fma4(s0, sc, Vp[lane]);
        fma4(s1, sc, Vp[lane + 64]);
    }
    ((float4*)accbuf[wv])[lane]      = s0;
    ((float4*)accbuf[wv])[lane + 64] = s1;

    // ---- 3. per-row weights / inverse denominators (wave 0) ----
    if (wv == 0) {
        const float e_j = (lane < L) ? p_loc[(size_t)b * T + t0 + lane] : 0.f;
        float ce = e_j;
#pragma unroll
        for (int off = 1; off < 32; off <<= 1) {
            const float t = __shfl_up(ce, off);
            if (lane >= off) ce += t;
        }
        if (lane < L) {
            wl[lane] = sck * e_j;
            il[lane] = 1.0f / fmaf(sck, ce, Qexcl);
        }
    }
    __syncthreads();

    float4 seed0, seed1;
    {
        const float4 c0 = ((float4*)accbuf[0])[lane];
        const float4 c1 = ((float4*)accbuf[1])[lane];
        const float4 c2 = ((float4*)accbuf[2])[lane];
        const float4 c3 = ((float4*)accbuf[3])[lane];
        seed0.x = (c0.x + c1.x) + (c2.x + c3.x);
        seed0.y = (c0.y + c1.y) + (c2.y + c3.y);
        seed0.z = (c0.z + c1.z) + (c2.z + c3.z);
        seed0.w = (c0.w + c1.w) + (c2.w + c3.w);
        const float4 d0 = ((float4*)accbuf[0])[lane + 64];
        const float4 d1 = ((float4*)accbuf[1])[lane + 64];
        const float4 d2 = ((float4*)accbuf[2])[lane + 64];
        const float4 d3 = ((float4*)accbuf[3])[lane + 64];
        seed1.x = (d0.x + d1.x) + (d2.x + d3.x);
        seed1.y = (d0.y + d1.y) + (d2.y + d3.y);
        seed1.z = (d0.z + d1.z) + (d2.z + d3.z);
        seed1.w = (d0.w + d1.w) + (d2.w + d3.w);
    }

    // ---- 4. per-wave partial over its 8 rows, then seeded scan ----
    float wcr[8], ilr[8];
    float4 t0v = {0.f, 0.f, 0.f, 0.f}, t1v = {0.f, 0.f, 0.f, 0.f};
#pragma unroll
    for (int r = 0; r < 8; ++r) {
        wcr[r] = wl[wv * 8 + r];
        ilr[r] = il[wv * 8 + r];
        fma4(t0v, wcr[r], xr0[r]); fma4(t1v, wcr[r], xr1[r]);
    }
    __syncthreads();                       // seed reads complete
    ((float4*)accbuf[wv])[lane]      = t0v;
    ((float4*)accbuf[wv])[lane + 64] = t1v;
    __syncthreads();

    float4 p0 = seed0, p1 = seed1;
    for (int w2 = 0; w2 < wv; ++w2) {      // wave-uniform loop
        const float4 c0 = ((float4*)accbuf[w2])[lane];
        const float4 c1 = ((float4*)accbuf[w2])[lane + 64];
        p0.x += c0.x; p0.y += c0.y; p0.z += c0.z; p0.w += c0.w;
        p1.x += c1.x; p1.y += c1.y; p1.z += c1.z; p1.w += c1.w;
    }

    float4* outb = (float4*)out + (size_t)b * T * D4;
    if (k == 0 && wv == 0) {               // out[b,0,:] = x[b,0,:]
        outb[lane]      = xr0[0];
        outb[lane + 64] = xr1[0];
    }
#pragma unroll
    for (int r = 0; r < 8; ++r) {
        fma4(p0, wcr[r], xr0[r]); fma4(p1, wcr[r], xr1[r]);
        const int t = t0 + wv * 8 + r;
        if (t < T - 1) {
            const float idn = ilr[r];
            float4 o0, o1;
            o0.x = p0.x * idn; o0.y = p0.y * idn; o0.z = p0.z * idn; o0.w = p0.w * idn;
            o1.x = p1.x * idn; o1.y = p1.y * idn; o1.z = p1.z * idn; o1.w = p1.w * idn;
            outb[(size_t)(t + 1) * D4 + lane]      = o0;
            outb[(size_t)(t + 1) * D4 + lane + 64] = o1;
        }
    }
}

// ---------------------------------------------------------------------------
extern "C" void kernel_launch(void* const* d_in, const int* in_sizes, int n_in,
                              void* d_out, int out_size, void* d_ws, size_t ws_size,
                              hipStream_t stream) {
    const float* x    = (const float*)d_in[0];
    const float* w    = (const float*)d_in[1];
    const float* bias = (const float*)d_in[2];
    float* out = (float*)d_out;

    // workspace layout (fp32): p_loc[B*T] | m[B*NS] | q[B*NS] | V[B*NS*D]
    float* p_loc = (float*)d_ws;
    float* m     = p_loc + (size_t)B * T;
    float* q     = m     + (size_t)B * NS;
    float* V     = q     + (size_t)B * NS;

    seg_kernel<<<B * NS, 256, 0, stream>>>(x, w, bias, p_loc, m, q, V);
    out_kernel<<<B * NS, 256, 0, stream>>>(x, p_loc, m, q, V, out);
}